// Round 4
// baseline (431.973 us; speedup 1.0000x reference)
//
#include <hip/hip_runtime.h>
#include <cstdint>
#include <cstddef>

#define N_TOK 2048
#define HID 1024
#define FDIM 1024
#define NE 8
#define PAIR_CAP 5120
#define MT 128
#define BK 64
#define THRESH 0.7f
#define NBLK 512

typedef __attribute__((ext_vector_type(8))) short bf16x8;
typedef __attribute__((ext_vector_type(4))) float f32x4;

static __device__ __forceinline__ unsigned short f2bf(float f) {
  unsigned int u = __float_as_uint(f);
  u += 0x7FFF + ((u >> 16) & 1);   // RNE
  return (unsigned short)(u >> 16);
}
static __device__ __forceinline__ float bf2f(unsigned short u) {
  return __uint_as_float(((unsigned int)u) << 16);
}

// async global->LDS, 16B per lane; lds dest = wave-uniform base + lane*16
static __device__ __forceinline__ void gl2lds16(const unsigned short* g, unsigned short* l) {
  __builtin_amdgcn_global_load_lds(
      (const __attribute__((address_space(1))) void*)g,
      (__attribute__((address_space(3))) void*)l, 16, 0, 0);
}

// Software grid barrier. Safe because grid (512) == resident capacity
// (launch_bounds(256,2) -> 2 blocks/CU x 256 CU; LDS 33.5KB -> 2/CU fits).
// One-shot arrival counter per barrier slot (zeroed by pre-launch memset).
// Device-scope atomics + __threadfence handle cross-XCD visibility (G16).
// Bounded spin: can never hang the container (worst case -> wrong result).
static __device__ __forceinline__ void gridbar(int* bar, int idx) {
  __syncthreads();
  if (threadIdx.x == 0) {
    __threadfence();                 // release prior writes
    atomicAdd(&bar[idx], 1);         // device-scope (m20)
    int spins = 0;
    while (__hip_atomic_load(&bar[idx], __ATOMIC_RELAXED,
                             __HIP_MEMORY_SCOPE_AGENT) < NBLK) {
      __builtin_amdgcn_s_sleep(8);
      if (++spins > (1 << 21)) break;   // failsafe, never hang
    }
    __threadfence();                 // acquire
  }
  __syncthreads();
}

// One fused kernel, 5 phases, software grid barriers between phases.
__global__ __launch_bounds__(256, 2) void k_fused(
    const float* __restrict__ x, const float* __restrict__ gw,
    const float* __restrict__ gup, const float* __restrict__ dwn,
    const float* __restrict__ sim, float* __restrict__ out,
    int* __restrict__ ctrl, unsigned short* __restrict__ xb,
    float* __restrict__ topw, int* __restrict__ topi,
    int* __restrict__ ptok, float* __restrict__ pw, int* __restrict__ pot,
    unsigned short* __restrict__ hmid, unsigned short* __restrict__ yb,
    unsigned short* __restrict__ gupb, unsigned short* __restrict__ dwnb) {
  // LDS union: router sgw (32KB) | GEMM As(16K)+Bs(16K)+toks(512B)
  __shared__ __align__(16) unsigned char smem[MT * BK * 2 + 128 * BK * 2 + 512];
  unsigned short* As = (unsigned short*)smem;
  unsigned short* Bs = As + MT * BK;
  int* toks = (int*)(smem + MT * BK * 2 + 128 * BK * 2);
  int* bar = ctrl + 8;   // 4 barrier slots at ctrl[8..11]

  int t = threadIdx.x;
  int bid = blockIdx.x;
  int lane = t & 63;
  int wave = t >> 6;
  int lm = lane & 15, lh = lane >> 4;
  int wm = wave >> 1, wn = wave & 1;

  // ================= P0a: router (4 tokens per block; x -> xb bf16)
  {
    float* sgw = (float*)smem;
#pragma unroll
    for (int i = 0; i < NE * HID / 256; ++i) sgw[t + 256 * i] = gw[t + 256 * i];
    __syncthreads();
    int n = bid * 4 + wave;
    float acc[NE];
#pragma unroll
    for (int e = 0; e < NE; ++e) acc[e] = 0.f;
#pragma unroll
    for (int i = 0; i < HID / 64; ++i) {
      int h = i * 64 + lane;
      float xv = x[(size_t)n * HID + h];
      xb[(size_t)n * HID + h] = f2bf(xv);
#pragma unroll
      for (int e = 0; e < NE; ++e) acc[e] += xv * sgw[e * HID + h];
    }
#pragma unroll
    for (int off = 32; off > 0; off >>= 1) {
#pragma unroll
      for (int e = 0; e < NE; ++e) acc[e] += __shfl_xor(acc[e], off, 64);
    }
    if (lane == 0) {
      float m = acc[0];
      for (int e = 1; e < NE; ++e) m = fmaxf(m, acc[e]);
      float p[NE]; float s = 0.f;
      for (int e = 0; e < NE; ++e) { p[e] = __expf(acc[e] - m); s += p[e]; }
      float inv = 1.f / s;
      for (int e = 0; e < NE; ++e) p[e] *= inv;
      int i0 = 0; float b0 = p[0];
      for (int e = 1; e < NE; ++e) if (p[e] > b0) { b0 = p[e]; i0 = e; }
      int i1 = -1; float b1 = -1.f;
      for (int e = 0; e < NE; ++e) { if (e == i0) continue; if (p[e] > b1) { b1 = p[e]; i1 = e; } }
      float sw = b0 + b1; if (sw < 1e-12f) sw = 1e-12f;
      topw[n * 2] = b0 / sw; topw[n * 2 + 1] = b1 / sw;
      topi[n * 2] = i0;      topi[n * 2 + 1] = i1;
    }
  }
  // ================= P0b: gate_up fp32 -> bf16 (grid-stride)
  {
    const int n4g = NE * 2 * FDIM * HID / 4;
    for (int i = bid * 256 + t; i < n4g; i += NBLK * 256) {
      float4 v = ((const float4*)gup)[i];
      ushort4 o;
      o.x = f2bf(v.x); o.y = f2bf(v.y); o.z = f2bf(v.z); o.w = f2bf(v.w);
      ((ushort4*)gupb)[i] = o;
    }
  }
  gridbar(bar, 0);

  // ================= P1: pairs (block 0) || down_proj cvt (blocks 1..511)
  if (bid == 0) {
    __shared__ int prim[NE], emap[NE], cnt[NE], soff[NE], cur[NE], padc[NE];
    if (t < NE) { prim[t] = 0; cnt[t] = 0; }
    __syncthreads();
    for (int n = t; n < N_TOK; n += 256) prim[topi[n * 2]] = 1;   // S=1
    __syncthreads();
    if (t < NE) {
      float best = -1e30f; int bj = -1;
      for (int j = 0; j < NE; ++j) {
        if (prim[j]) {
          float s = sim[t * NE + j];
          if (s > best) { best = s; bj = j; }   // strict >: first-index argmax
        }
      }
      int m = t;
      if (!prim[t] && bj >= 0 && best >= THRESH) m = bj;
      emap[t] = m;
    }
    __syncthreads();
    for (int n = t; n < N_TOK; n += 256) {
      atomicAdd(&cnt[emap[topi[n * 2]]], 1);
      atomicAdd(&cnt[emap[topi[n * 2 + 1]]], 1);
    }
    __syncthreads();
    if (t == 0) {
      int o = 0;
      int w = 0;
      for (int e = 0; e < NE; ++e) {
        soff[e] = o;
        int p = (cnt[e] + MT - 1) & ~(MT - 1);
        padc[e] = p; cur[e] = 0; o += p;
        for (int m = 0; m < p / MT; ++m) ctrl[40 + w++] = (e << 16) | m;
      }
      ctrl[1] = w;
    }
    __syncthreads();
    if (t < NE) { ctrl[24 + t] = soff[t]; ctrl[32 + t] = padc[t]; }
    for (int n = t; n < N_TOK; n += 256) {
      int i0 = topi[n * 2], i1 = topi[n * 2 + 1];
      int e0 = emap[i0], e1 = emap[i1];
      int s0 = soff[e0] + atomicAdd(&cur[e0], 1);
      int s1 = soff[e1] + atomicAdd(&cur[e1], 1);
      ptok[s0] = n; pw[s0] = topw[n * 2];
      ptok[s1] = n; pw[s1] = topw[n * 2 + 1];
      pot[n * 2] = s0; pot[n * 2 + 1] = s1;
    }
    __syncthreads();
    for (int e = 0; e < NE; ++e) {
      for (int s = cnt[e] + t; s < padc[e]; s += 256) {
        ptok[soff[e] + s] = 0; pw[soff[e] + s] = 0.f;   // padding
      }
    }
  } else {
    const int n4d = NE * HID * FDIM / 4;
    for (int i = (bid - 1) * 256 + t; i < n4d; i += (NBLK - 1) * 256) {
      float4 v = ((const float4*)dwn)[i];
      ushort4 o;
      o.x = f2bf(v.x); o.y = f2bf(v.y); o.z = f2bf(v.z); o.w = f2bf(v.w);
      ((ushort4*)dwnb)[i] = o;
    }
  }
  gridbar(bar, 1);

  int nmt = ctrl[1];

  // ================= P2: GEMM1 (128 slots x 64 f, gate+up interleaved).
  // LDS: rows x 8 chunks of 16B; physical chunk p ^ (r&7) (2-way aliasing, free)
  for (int wi = bid; wi < nmt * 16; wi += NBLK) {
    int i4 = wi >> 4;
    int wlv = ctrl[40 + i4];
    int e = wlv >> 16;
    int mt = wlv & 0xffff;
    int y = wi & 15;
    int base = ctrl[24 + e] + mt * MT;
    int f0 = y * 64;

    if (t < MT) toks[t] = ptok[base + t];
    __syncthreads();

    f32x4 acc[4][4] = {};
    const unsigned short* gbase = gupb + (size_t)e * 2 * FDIM * HID;

    for (int k0 = 0; k0 < HID; k0 += BK) {
#pragma unroll
      for (int i = 0; i < 4; ++i) {
        int q = i * 256 + t;
        int r = q >> 3;
        int cl = (q & 7) ^ (r & 7);
        gl2lds16(xb + (size_t)toks[r] * HID + k0 + cl * 8, &As[(q & ~63) * 8]);
      }
#pragma unroll
      for (int i = 0; i < 4; ++i) {
        int q = i * 256 + t;
        int r = q >> 3;
        int cl = (q & 7) ^ (r & 7);
        int grow = ((r >> 4) & 1) * FDIM + f0 + ((r >> 5) << 4) + (r & 15);
        gl2lds16(gbase + (size_t)grow * HID + k0 + cl * 8, &Bs[(q & ~63) * 8]);
      }
      __syncthreads();
#pragma unroll
      for (int kk = 0; kk < 2; ++kk) {
        bf16x8 af[4], bfr[4];
#pragma unroll
        for (int rb = 0; rb < 4; ++rb) {
          int row = wm * 64 + rb * 16 + lm;
          int p = (kk * 4 + lh) ^ (row & 7);
          af[rb] = *(const bf16x8*)(&As[row * BK + p * 8]);
        }
#pragma unroll
        for (int cc = 0; cc < 4; ++cc) {
          int row = wn * 64 + cc * 16 + lm;
          int p = (kk * 4 + lh) ^ (row & 7);
          bfr[cc] = *(const bf16x8*)(&Bs[row * BK + p * 8]);
        }
#pragma unroll
        for (int rb = 0; rb < 4; ++rb) {
#pragma unroll
          for (int cc = 0; cc < 4; ++cc)
            acc[rb][cc] = __builtin_amdgcn_mfma_f32_16x16x32_bf16(af[rb], bfr[cc], acc[rb][cc], 0, 0, 0);
        }
      }
      __syncthreads();
    }
    // epilogue: silu(gate)*up; f = f0 + wn*32 + fb*16 + lm
#pragma unroll
    for (int rb = 0; rb < 4; ++rb) {
      int slot = base + wm * 64 + rb * 16 + lh * 4;
#pragma unroll
      for (int fb = 0; fb < 2; ++fb) {
        f32x4 g = acc[rb][fb * 2];
        f32x4 u = acc[rb][fb * 2 + 1];
        int f = f0 + wn * 32 + fb * 16 + lm;
#pragma unroll
        for (int reg = 0; reg < 4; ++reg) {
          float gv = g[reg];
          float hm = gv / (1.f + __expf(-gv)) * u[reg];
          hmid[(size_t)(slot + reg) * FDIM + f] = f2bf(hm);
        }
      }
    }
    __syncthreads();
  }
  gridbar(bar, 2);

  // ================= P3: GEMM2 (128 slots x 128 h) -> yb bf16
  for (int wi = bid; wi < nmt * 8; wi += NBLK) {
    int i4 = wi >> 3;
    int wlv = ctrl[40 + i4];
    int e = wlv >> 16;
    int mt = wlv & 0xffff;
    int y = wi & 7;
    int base = ctrl[24 + e] + mt * MT;
    int h0 = y * 128;

    f32x4 acc[4][4] = {};
    const unsigned short* dbase = dwnb + (size_t)e * HID * FDIM;

    for (int k0 = 0; k0 < FDIM; k0 += BK) {
#pragma unroll
      for (int i = 0; i < 4; ++i) {
        int q = i * 256 + t;
        int r = q >> 3;
        int cl = (q & 7) ^ (r & 7);
        gl2lds16(hmid + (size_t)(base + r) * FDIM + k0 + cl * 8, &As[(q & ~63) * 8]);
      }
#pragma unroll
      for (int i = 0; i < 4; ++i) {
        int q = i * 256 + t;
        int r = q >> 3;
        int cl = (q & 7) ^ (r & 7);
        gl2lds16(dbase + (size_t)(h0 + r) * FDIM + k0 + cl * 8, &Bs[(q & ~63) * 8]);
      }
      __syncthreads();
#pragma unroll
      for (int kk = 0; kk < 2; ++kk) {
        bf16x8 af[4], bfr[4];
#pragma unroll
        for (int rb = 0; rb < 4; ++rb) {
          int row = wm * 64 + rb * 16 + lm;
          int p = (kk * 4 + lh) ^ (row & 7);
          af[rb] = *(const bf16x8*)(&As[row * BK + p * 8]);
        }
#pragma unroll
        for (int cc = 0; cc < 4; ++cc) {
          int row = wn * 64 + cc * 16 + lm;
          int p = (kk * 4 + lh) ^ (row & 7);
          bfr[cc] = *(const bf16x8*)(&Bs[row * BK + p * 8]);
        }
#pragma unroll
        for (int rb = 0; rb < 4; ++rb) {
#pragma unroll
          for (int cc = 0; cc < 4; ++cc)
            acc[rb][cc] = __builtin_amdgcn_mfma_f32_16x16x32_bf16(af[rb], bfr[cc], acc[rb][cc], 0, 0, 0);
        }
      }
      __syncthreads();
    }
#pragma unroll
    for (int rb = 0; rb < 4; ++rb) {
      int slot = base + wm * 64 + rb * 16 + lh * 4;
#pragma unroll
      for (int cc = 0; cc < 4; ++cc) {
        int h = h0 + wn * 64 + cc * 16 + lm;
#pragma unroll
        for (int reg = 0; reg < 4; ++reg)
          yb[(size_t)(slot + reg) * HID + h] = f2bf(acc[rb][cc][reg]);
      }
    }
    __syncthreads();
  }
  gridbar(bar, 3);

  // ================= P4: combine: out[n] = w0*y[p0] + w1*y[p1]
#pragma unroll
  for (int tk = 0; tk < 4; ++tk) {
    int n = bid * 4 + tk;
    int p0 = pot[n * 2], p1 = pot[n * 2 + 1];
    float w0 = pw[p0], w1 = pw[p1];
    int h = t * 4;
    ushort4 a = *(const ushort4*)(yb + (size_t)p0 * HID + h);
    ushort4 b = *(const ushort4*)(yb + (size_t)p1 * HID + h);
    float4 o;
    o.x = w0 * bf2f(a.x) + w1 * bf2f(b.x);
    o.y = w0 * bf2f(a.y) + w1 * bf2f(b.y);
    o.z = w0 * bf2f(a.z) + w1 * bf2f(b.z);
    o.w = w0 * bf2f(a.w) + w1 * bf2f(b.w);
    *(float4*)(out + (size_t)n * HID + h) = o;
  }
}

extern "C" void kernel_launch(void* const* d_in, const int* in_sizes, int n_in,
                              void* d_out, int out_size, void* d_ws, size_t ws_size,
                              hipStream_t stream) {
  (void)in_sizes; (void)n_in; (void)out_size; (void)ws_size;
  const float* x   = (const float*)d_in[0];
  const float* gw  = (const float*)d_in[1];
  const float* gup = (const float*)d_in[2];
  const float* dwn = (const float*)d_in[3];
  const float* sim = (const float*)d_in[4];
  float* out = (float*)d_out;

  char* w = (char*)d_ws;
  int* ctrl = (int*)w;
  size_t off = 512;
  unsigned short* xb = (unsigned short*)(w + off); off += (size_t)N_TOK * HID * 2;
  float* topw = (float*)(w + off); off += (size_t)N_TOK * 2 * 4;
  int*   topi = (int*)(w + off);   off += (size_t)N_TOK * 2 * 4;
  int*   ptok = (int*)(w + off);   off += (size_t)PAIR_CAP * 4;
  float* pw   = (float*)(w + off); off += (size_t)PAIR_CAP * 4;
  int*   pot  = (int*)(w + off);   off += (size_t)N_TOK * 2 * 4;
  unsigned short* hmid = (unsigned short*)(w + off); off += (size_t)PAIR_CAP * FDIM * 2;
  unsigned short* yb   = (unsigned short*)(w + off); off += (size_t)PAIR_CAP * HID * 2;
  unsigned short* gupb = (unsigned short*)(w + off); off += (size_t)NE * 2 * FDIM * HID * 2;
  unsigned short* dwnb = (unsigned short*)(w + off); off += (size_t)NE * HID * FDIM * 2;

  // zero ctrl (incl. the 4 barrier counters) each iteration; workspace is poisoned
  hipMemsetAsync(ctrl, 0, 512, stream);
  k_fused<<<dim3(NBLK), dim3(256), 0, stream>>>(
      x, gw, gup, dwn, sim, out, ctrl, xb, topw, topi,
      ptok, pw, pot, hmid, yb, gupb, dwnb);
}

// Round 5
// 209.780 us; speedup vs baseline: 2.0592x; 2.0592x over previous
//
#include <hip/hip_runtime.h>
#include <cstdint>
#include <cstddef>

#define N_TOK 2048
#define HID 1024
#define FDIM 1024
#define NE 8
#define PAIR_CAP 5120
#define MT 128
#define BK 64
#define THRESH 0.7f

typedef __attribute__((ext_vector_type(8))) short bf16x8;
typedef __attribute__((ext_vector_type(4))) float f32x4;

static __device__ __forceinline__ unsigned short f2bf(float f) {
  unsigned int u = __float_as_uint(f);
  u += 0x7FFF + ((u >> 16) & 1);   // RNE
  return (unsigned short)(u >> 16);
}
static __device__ __forceinline__ float bf2f(unsigned short u) {
  return __uint_as_float(((unsigned int)u) << 16);
}

// async global->LDS, 16B per lane; lds dest = wave-uniform base + lane*16
static __device__ __forceinline__ void gl2lds16(const unsigned short* g, unsigned short* l) {
  __builtin_amdgcn_global_load_lds(
      (const __attribute__((address_space(1))) void*)g,
      (__attribute__((address_space(3))) void*)l, 16, 0, 0);
}

// load 8 fp32 from global, convert RNE, return bf16x8 (for reg-staged B)
static __device__ __forceinline__ bf16x8 ld8cvt(const float* g) {
  float4 v0 = *(const float4*)g;
  float4 v1 = *(const float4*)(g + 4);
  bf16x8 o;
  o[0] = (short)f2bf(v0.x); o[1] = (short)f2bf(v0.y);
  o[2] = (short)f2bf(v0.z); o[3] = (short)f2bf(v0.w);
  o[4] = (short)f2bf(v1.x); o[5] = (short)f2bf(v1.y);
  o[6] = (short)f2bf(v1.z); o[7] = (short)f2bf(v1.w);
  return o;
}

// ---------------- Router: fp32 logits -> softmax -> top2 (+norm); x -> bf16
__global__ __launch_bounds__(256) void k_router(
    const float* __restrict__ x, const float* __restrict__ gw,
    unsigned short* __restrict__ xb, float* __restrict__ topw,
    int* __restrict__ topi) {
  __shared__ float sgw[NE * HID];
  int t = threadIdx.x;
#pragma unroll
  for (int i = 0; i < NE * HID / 256; ++i) sgw[t + 256 * i] = gw[t + 256 * i];
  __syncthreads();
  int lane = t & 63;
  int wave = t >> 6;
  int n = blockIdx.x * 4 + wave;
  float acc[NE];
#pragma unroll
  for (int e = 0; e < NE; ++e) acc[e] = 0.f;
#pragma unroll
  for (int i = 0; i < HID / 64; ++i) {
    int h = i * 64 + lane;
    float xv = x[(size_t)n * HID + h];
    xb[(size_t)n * HID + h] = f2bf(xv);
#pragma unroll
    for (int e = 0; e < NE; ++e) acc[e] += xv * sgw[e * HID + h];
  }
#pragma unroll
  for (int off = 32; off > 0; off >>= 1) {
#pragma unroll
    for (int e = 0; e < NE; ++e) acc[e] += __shfl_xor(acc[e], off, 64);
  }
  if (lane == 0) {
    float m = acc[0];
    for (int e = 1; e < NE; ++e) m = fmaxf(m, acc[e]);
    float p[NE]; float s = 0.f;
    for (int e = 0; e < NE; ++e) { p[e] = __expf(acc[e] - m); s += p[e]; }
    float inv = 1.f / s;
    for (int e = 0; e < NE; ++e) p[e] *= inv;
    int i0 = 0; float b0 = p[0];
    for (int e = 1; e < NE; ++e) if (p[e] > b0) { b0 = p[e]; i0 = e; }
    int i1 = -1; float b1 = -1.f;
    for (int e = 0; e < NE; ++e) { if (e == i0) continue; if (p[e] > b1) { b1 = p[e]; i1 = e; } }
    float sw = b0 + b1; if (sw < 1e-12f) sw = 1e-12f;
    topw[n * 2] = b0 / sw; topw[n * 2 + 1] = b1 / sw;
    topi[n * 2] = i0;      topi[n * 2 + 1] = i1;
  }
}

// ---------------- Pairs: primary mask, expert_map, compact slot lists + work list
// ctrl[1] = total mtiles; ctrl[24+e] = soff; ctrl[32+e] = padc; ctrl[40+i] = (e<<16)|mt
__global__ __launch_bounds__(256) void k_pairs(
    const float* __restrict__ sim, const int* __restrict__ topi,
    const float* __restrict__ topw, int* __restrict__ ctrl,
    int* __restrict__ ptok, float* __restrict__ pw, int* __restrict__ pot) {
  __shared__ int prim[NE], emap[NE], cnt[NE], soff[NE], cur[NE], padc[NE];
  int t = threadIdx.x;
  if (t < NE) { prim[t] = 0; cnt[t] = 0; }
  __syncthreads();
  for (int n = t; n < N_TOK; n += 256) prim[topi[n * 2]] = 1;   // S=1: union of top-1
  __syncthreads();
  if (t < NE) {
    float best = -1e30f; int bj = -1;
    for (int j = 0; j < NE; ++j) {
      if (prim[j]) {
        float s = sim[t * NE + j];
        if (s > best) { best = s; bj = j; }   // strict >: first-index argmax like jnp
      }
    }
    int m = t;
    if (!prim[t] && bj >= 0 && best >= THRESH) m = bj;
    emap[t] = m;
  }
  __syncthreads();
  for (int n = t; n < N_TOK; n += 256) {
    atomicAdd(&cnt[emap[topi[n * 2]]], 1);
    atomicAdd(&cnt[emap[topi[n * 2 + 1]]], 1);
  }
  __syncthreads();
  if (t == 0) {
    int o = 0;
    int w = 0;
    for (int e = 0; e < NE; ++e) {
      soff[e] = o;
      int p = (cnt[e] + MT - 1) & ~(MT - 1);
      padc[e] = p; cur[e] = 0; o += p;
      for (int m = 0; m < p / MT; ++m) ctrl[40 + w++] = (e << 16) | m;
    }
    ctrl[1] = w;
  }
  __syncthreads();
  if (t < NE) { ctrl[24 + t] = soff[t]; ctrl[32 + t] = padc[t]; }
  for (int n = t; n < N_TOK; n += 256) {
    int i0 = topi[n * 2], i1 = topi[n * 2 + 1];
    int e0 = emap[i0], e1 = emap[i1];
    int s0 = soff[e0] + atomicAdd(&cur[e0], 1);
    int s1 = soff[e1] + atomicAdd(&cur[e1], 1);
    ptok[s0] = n; pw[s0] = topw[n * 2];
    ptok[s1] = n; pw[s1] = topw[n * 2 + 1];
    pot[n * 2] = s0; pot[n * 2 + 1] = s1;
  }
  __syncthreads();
  for (int e = 0; e < NE; ++e) {
    for (int s = cnt[e] + t; s < padc[e]; s += 256) {
      ptok[soff[e] + s] = 0; pw[soff[e] + s] = 0.f;   // padding: token 0, weight 0
    }
  }
}

// LDS layout both GEMMs: rows x 8 chunks of 16B (64 bf16). Physical chunk of
// row r holds logical chunk p ^ (r&7): async A-writes stay lane-contiguous,
// fragment ds_read_b128 sees only 2-way bank aliasing (free, m136).
// B staged from fp32 weights global->reg->f2bf->ds_write (kills the cvt pass).
// gl2lds layout note: slot q (=row*8+chunk) lives at LDS elems [q*8, q*8+8).

// ---------------- GEMM1: 128 slots x 64 f (gate+up interleaved per-16).
// acc[4][4], 32 MFMA/wave/K-step. Work-list driven: b = i*16 + y.
__global__ __launch_bounds__(256, 2) void k_gemm1(
    const unsigned short* __restrict__ xb, const float* __restrict__ gup,
    unsigned short* __restrict__ hmid, const int* __restrict__ ptok,
    const int* __restrict__ ctrl) {
  int b = blockIdx.x;
  int i4 = b >> 4;
  if (i4 >= ctrl[1]) return;
  int wlv = ctrl[40 + i4];
  int e = wlv >> 16;
  int mt = wlv & 0xffff;
  int y = b & 15;
  int base = ctrl[24 + e] + mt * MT;
  int f0 = y * 64;

  __shared__ unsigned short As[MT * BK];    // 16 KB
  __shared__ unsigned short Bs[128 * BK];   // 16 KB
  __shared__ int toks[MT];

  int t = threadIdx.x;
  if (t < MT) toks[t] = ptok[base + t];
  __syncthreads();

  int lane = t & 63;
  int wave = t >> 6;
  int wm = wave >> 1, wn = wave & 1;
  int lm = lane & 15, lh = lane >> 4;

  f32x4 acc[4][4] = {};
  const float* gbase = gup + (size_t)e * 2 * FDIM * HID;

  for (int k0 = 0; k0 < HID; k0 += BK) {
    // A: 128 rows x 64 bf16, async token gather
#pragma unroll
    for (int i = 0; i < 4; ++i) {
      int q = i * 256 + t;
      int r = q >> 3;
      int cl = (q & 7) ^ (r & 7);
      gl2lds16(xb + (size_t)toks[r] * HID + k0 + cl * 8, &As[(q & ~63) * 8]);
    }
    // B: 128 rows fp32 -> bf16 reg-staged; row r -> type=(r>>4)&1, fb=r>>5, fl=r&15
#pragma unroll
    for (int i = 0; i < 4; ++i) {
      int q = i * 256 + t;
      int r = q >> 3;
      int cl = (q & 7) ^ (r & 7);
      int grow = ((r >> 4) & 1) * FDIM + f0 + ((r >> 5) << 4) + (r & 15);
      bf16x8 o = ld8cvt(gbase + (size_t)grow * HID + k0 + cl * 8);
      *(bf16x8*)(&Bs[q * 8]) = o;
    }
    __syncthreads();
#pragma unroll
    for (int kk = 0; kk < 2; ++kk) {
      bf16x8 af[4], bfr[4];
#pragma unroll
      for (int rb = 0; rb < 4; ++rb) {
        int row = wm * 64 + rb * 16 + lm;
        int p = (kk * 4 + lh) ^ (row & 7);
        af[rb] = *(const bf16x8*)(&As[row * BK + p * 8]);
      }
#pragma unroll
      for (int cc = 0; cc < 4; ++cc) {
        int row = wn * 64 + cc * 16 + lm;
        int p = (kk * 4 + lh) ^ (row & 7);
        bfr[cc] = *(const bf16x8*)(&Bs[row * BK + p * 8]);
      }
#pragma unroll
      for (int rb = 0; rb < 4; ++rb) {
#pragma unroll
        for (int cc = 0; cc < 4; ++cc)
          acc[rb][cc] = __builtin_amdgcn_mfma_f32_16x16x32_bf16(af[rb], bfr[cc], acc[rb][cc], 0, 0, 0);
      }
    }
    __syncthreads();
  }
  // epilogue: cc = {gate fb0, up fb0, gate fb1, up fb1}; f = f0+wn*32+fb*16+lm
#pragma unroll
  for (int rb = 0; rb < 4; ++rb) {
    int slot = base + wm * 64 + rb * 16 + lh * 4;
#pragma unroll
    for (int fb = 0; fb < 2; ++fb) {
      f32x4 g = acc[rb][fb * 2];
      f32x4 u = acc[rb][fb * 2 + 1];
      int f = f0 + wn * 32 + fb * 16 + lm;
#pragma unroll
      for (int reg = 0; reg < 4; ++reg) {
        float gv = g[reg];
        float hm = gv / (1.f + __expf(-gv)) * u[reg];
        hmid[(size_t)(slot + reg) * FDIM + f] = f2bf(hm);
      }
    }
  }
}

// ---------------- GEMM2: 128 slots x 128 h -> yb bf16; B reg-staged from fp32.
// b = i*8 + y.
__global__ __launch_bounds__(256, 2) void k_gemm2(
    const unsigned short* __restrict__ hmid, const float* __restrict__ dwn,
    unsigned short* __restrict__ yb, const int* __restrict__ ctrl) {
  int b = blockIdx.x;
  int i4 = b >> 3;
  if (i4 >= ctrl[1]) return;
  int wlv = ctrl[40 + i4];
  int e = wlv >> 16;
  int mt = wlv & 0xffff;
  int y = b & 7;
  int base = ctrl[24 + e] + mt * MT;
  int h0 = y * 128;

  __shared__ unsigned short As[MT * BK];    // 16 KB
  __shared__ unsigned short Bs[128 * BK];   // 16 KB

  int t = threadIdx.x;
  int lane = t & 63;
  int wave = t >> 6;
  int wm = wave >> 1, wn = wave & 1;
  int lm = lane & 15, lh = lane >> 4;

  f32x4 acc[4][4] = {};
  const float* dbase = dwn + (size_t)e * HID * FDIM;

  for (int k0 = 0; k0 < FDIM; k0 += BK) {
#pragma unroll
    for (int i = 0; i < 4; ++i) {
      int q = i * 256 + t;
      int r = q >> 3;
      int cl = (q & 7) ^ (r & 7);
      gl2lds16(hmid + (size_t)(base + r) * FDIM + k0 + cl * 8, &As[(q & ~63) * 8]);
    }
#pragma unroll
    for (int i = 0; i < 4; ++i) {
      int q = i * 256 + t;
      int r = q >> 3;
      int cl = (q & 7) ^ (r & 7);
      bf16x8 o = ld8cvt(dbase + (size_t)(h0 + r) * FDIM + k0 + cl * 8);
      *(bf16x8*)(&Bs[q * 8]) = o;
    }
    __syncthreads();
#pragma unroll
    for (int kk = 0; kk < 2; ++kk) {
      bf16x8 af[4], bfr[4];
#pragma unroll
      for (int rb = 0; rb < 4; ++rb) {
        int row = wm * 64 + rb * 16 + lm;
        int p = (kk * 4 + lh) ^ (row & 7);
        af[rb] = *(const bf16x8*)(&As[row * BK + p * 8]);
      }
#pragma unroll
      for (int cc = 0; cc < 4; ++cc) {
        int row = wn * 64 + cc * 16 + lm;
        int p = (kk * 4 + lh) ^ (row & 7);
        bfr[cc] = *(const bf16x8*)(&Bs[row * BK + p * 8]);
      }
#pragma unroll
      for (int rb = 0; rb < 4; ++rb) {
#pragma unroll
        for (int cc = 0; cc < 4; ++cc)
          acc[rb][cc] = __builtin_amdgcn_mfma_f32_16x16x32_bf16(af[rb], bfr[cc], acc[rb][cc], 0, 0, 0);
      }
    }
    __syncthreads();
  }
#pragma unroll
  for (int rb = 0; rb < 4; ++rb) {
    int slot = base + wm * 64 + rb * 16 + lh * 4;
#pragma unroll
    for (int cc = 0; cc < 4; ++cc) {
      int h = h0 + wn * 64 + cc * 16 + lm;
#pragma unroll
      for (int reg = 0; reg < 4; ++reg)
        yb[(size_t)(slot + reg) * HID + h] = f2bf(acc[rb][cc][reg]);
    }
  }
}

// ---------------- Combine: out[n] = w0*y[p0] + w1*y[p1]
__global__ __launch_bounds__(256) void k_combine(
    const unsigned short* __restrict__ yb, const float* __restrict__ pw,
    const int* __restrict__ pot, float* __restrict__ out) {
  int n = blockIdx.x;
  int t = threadIdx.x;
  int p0 = pot[n * 2], p1 = pot[n * 2 + 1];
  float w0 = pw[p0], w1 = pw[p1];
  int h = t * 4;
  ushort4 a = *(const ushort4*)(yb + (size_t)p0 * HID + h);
  ushort4 b = *(const ushort4*)(yb + (size_t)p1 * HID + h);
  float4 o;
  o.x = w0 * bf2f(a.x) + w1 * bf2f(b.x);
  o.y = w0 * bf2f(a.y) + w1 * bf2f(b.y);
  o.z = w0 * bf2f(a.z) + w1 * bf2f(b.z);
  o.w = w0 * bf2f(a.w) + w1 * bf2f(b.w);
  *(float4*)(out + (size_t)n * HID + h) = o;
}

extern "C" void kernel_launch(void* const* d_in, const int* in_sizes, int n_in,
                              void* d_out, int out_size, void* d_ws, size_t ws_size,
                              hipStream_t stream) {
  (void)in_sizes; (void)n_in; (void)out_size; (void)ws_size;
  const float* x   = (const float*)d_in[0];
  const float* gw  = (const float*)d_in[1];
  const float* gup = (const float*)d_in[2];
  const float* dwn = (const float*)d_in[3];
  const float* sim = (const float*)d_in[4];
  float* out = (float*)d_out;

  char* w = (char*)d_ws;
  int* ctrl = (int*)w;
  size_t off = 512;
  unsigned short* xb = (unsigned short*)(w + off); off += (size_t)N_TOK * HID * 2;
  float* topw = (float*)(w + off); off += (size_t)N_TOK * 2 * 4;
  int*   topi = (int*)(w + off);   off += (size_t)N_TOK * 2 * 4;
  int*   ptok = (int*)(w + off);   off += (size_t)PAIR_CAP * 4;
  float* pw   = (float*)(w + off); off += (size_t)PAIR_CAP * 4;
  int*   pot  = (int*)(w + off);   off += (size_t)N_TOK * 2 * 4;
  unsigned short* hmid = (unsigned short*)(w + off); off += (size_t)PAIR_CAP * FDIM * 2;
  unsigned short* yb   = (unsigned short*)(w + off); off += (size_t)PAIR_CAP * HID * 2;

  k_router<<<N_TOK / 4, 256, 0, stream>>>(x, gw, xb, topw, topi);
  k_pairs<<<1, 256, 0, stream>>>(sim, topi, topw, ctrl, ptok, pw, pot);
  k_gemm1<<<dim3(40 * 16), 256, 0, stream>>>(xb, gup, hmid, ptok, ctrl);
  k_gemm2<<<dim3(40 * 8), 256, 0, stream>>>(hmid, dwn, yb, ctrl);
  k_combine<<<N_TOK, 256, 0, stream>>>(yb, pw, pot, out);
}

// Round 6
// 204.102 us; speedup vs baseline: 2.1165x; 1.0278x over previous
//
#include <hip/hip_runtime.h>
#include <cstdint>
#include <cstddef>

#define N_TOK 2048
#define HID 1024
#define FDIM 1024
#define NE 8
#define PAIR_CAP 5120
#define MT 128
#define BK 64
#define THRESH 0.7f

typedef __attribute__((ext_vector_type(8))) short bf16x8;
typedef __attribute__((ext_vector_type(4))) float f32x4;

static __device__ __forceinline__ unsigned short f2bf(float f) {
  unsigned int u = __float_as_uint(f);
  u += 0x7FFF + ((u >> 16) & 1);   // RNE
  return (unsigned short)(u >> 16);
}
static __device__ __forceinline__ float bf2f(unsigned short u) {
  return __uint_as_float(((unsigned int)u) << 16);
}

// async global->LDS, 16B per lane; lds dest = wave-uniform base + lane*16
static __device__ __forceinline__ void gl2lds16(const unsigned short* g, unsigned short* l) {
  __builtin_amdgcn_global_load_lds(
      (const __attribute__((address_space(1))) void*)g,
      (__attribute__((address_space(3))) void*)l, 16, 0, 0);
}

// ---------------- Router (blocks 0..511) + weight cvt fp32->bf16 (rest)
__global__ __launch_bounds__(256) void k_rc(
    const float* __restrict__ x, const float* __restrict__ gw,
    unsigned short* __restrict__ xb, float* __restrict__ topw,
    int* __restrict__ topi,
    const float* __restrict__ gup, unsigned short* __restrict__ gupb, int n4g,
    const float* __restrict__ dwn, unsigned short* __restrict__ dwnb, int n4d) {
  int bid = blockIdx.x;
  int t = threadIdx.x;
  if (bid >= 512) {
    int i = (bid - 512) * 256 + t;
    if (i < n4g) {
      float4 v = ((const float4*)gup)[i];
      ushort4 o;
      o.x = f2bf(v.x); o.y = f2bf(v.y); o.z = f2bf(v.z); o.w = f2bf(v.w);
      ((ushort4*)gupb)[i] = o;
    } else {
      int j = i - n4g;
      if (j < n4d) {
        float4 v = ((const float4*)dwn)[j];
        ushort4 o;
        o.x = f2bf(v.x); o.y = f2bf(v.y); o.z = f2bf(v.z); o.w = f2bf(v.w);
        ((ushort4*)dwnb)[j] = o;
      }
    }
    return;
  }
  __shared__ float sgw[NE * HID];
#pragma unroll
  for (int i = 0; i < NE * HID / 256; ++i) sgw[t + 256 * i] = gw[t + 256 * i];
  __syncthreads();
  int lane = t & 63;
  int wave = t >> 6;
  int n = bid * 4 + wave;
  float acc[NE];
#pragma unroll
  for (int e = 0; e < NE; ++e) acc[e] = 0.f;
#pragma unroll
  for (int i = 0; i < HID / 64; ++i) {
    int h = i * 64 + lane;
    float xv = x[(size_t)n * HID + h];
    xb[(size_t)n * HID + h] = f2bf(xv);
#pragma unroll
    for (int e = 0; e < NE; ++e) acc[e] += xv * sgw[e * HID + h];
  }
#pragma unroll
  for (int off = 32; off > 0; off >>= 1) {
#pragma unroll
    for (int e = 0; e < NE; ++e) acc[e] += __shfl_xor(acc[e], off, 64);
  }
  if (lane == 0) {
    float m = acc[0];
    for (int e = 1; e < NE; ++e) m = fmaxf(m, acc[e]);
    float p[NE]; float s = 0.f;
    for (int e = 0; e < NE; ++e) { p[e] = __expf(acc[e] - m); s += p[e]; }
    float inv = 1.f / s;
    for (int e = 0; e < NE; ++e) p[e] *= inv;
    int i0 = 0; float b0 = p[0];
    for (int e = 1; e < NE; ++e) if (p[e] > b0) { b0 = p[e]; i0 = e; }
    int i1 = -1; float b1 = -1.f;
    for (int e = 0; e < NE; ++e) { if (e == i0) continue; if (p[e] > b1) { b1 = p[e]; i1 = e; } }
    float sw = b0 + b1; if (sw < 1e-12f) sw = 1e-12f;
    topw[n * 2] = b0 / sw; topw[n * 2 + 1] = b1 / sw;
    topi[n * 2] = i0;      topi[n * 2 + 1] = i1;
  }
}

// ---------------- Pairs: primary mask, expert_map, compact slot lists + work list
// ctrl[1] = total mtiles; ctrl[24+e] = soff; ctrl[32+e] = padc; ctrl[40+i] = (e<<16)|mt
__global__ __launch_bounds__(256) void k_pairs(
    const float* __restrict__ sim, const int* __restrict__ topi,
    const float* __restrict__ topw, int* __restrict__ ctrl,
    int* __restrict__ ptok, float* __restrict__ pw, int* __restrict__ pot) {
  __shared__ int prim[NE], emap[NE], cnt[NE], soff[NE], cur[NE], padc[NE];
  int t = threadIdx.x;
  if (t < NE) { prim[t] = 0; cnt[t] = 0; }
  __syncthreads();
  for (int n = t; n < N_TOK; n += 256) prim[topi[n * 2]] = 1;   // S=1: union of top-1
  __syncthreads();
  if (t < NE) {
    float best = -1e30f; int bj = -1;
    for (int j = 0; j < NE; ++j) {
      if (prim[j]) {
        float s = sim[t * NE + j];
        if (s > best) { best = s; bj = j; }   // strict >: first-index argmax like jnp
      }
    }
    int m = t;
    if (!prim[t] && bj >= 0 && best >= THRESH) m = bj;
    emap[t] = m;
  }
  __syncthreads();
  for (int n = t; n < N_TOK; n += 256) {
    atomicAdd(&cnt[emap[topi[n * 2]]], 1);
    atomicAdd(&cnt[emap[topi[n * 2 + 1]]], 1);
  }
  __syncthreads();
  if (t == 0) {
    int o = 0;
    int w = 0;
    for (int e = 0; e < NE; ++e) {
      soff[e] = o;
      int p = (cnt[e] + MT - 1) & ~(MT - 1);
      padc[e] = p; cur[e] = 0; o += p;
      for (int m = 0; m < p / MT; ++m) ctrl[40 + w++] = (e << 16) | m;
    }
    ctrl[1] = w;
  }
  __syncthreads();
  if (t < NE) { ctrl[24 + t] = soff[t]; ctrl[32 + t] = padc[t]; }
  for (int n = t; n < N_TOK; n += 256) {
    int i0 = topi[n * 2], i1 = topi[n * 2 + 1];
    int e0 = emap[i0], e1 = emap[i1];
    int s0 = soff[e0] + atomicAdd(&cur[e0], 1);
    int s1 = soff[e1] + atomicAdd(&cur[e1], 1);
    ptok[s0] = n; pw[s0] = topw[n * 2];
    ptok[s1] = n; pw[s1] = topw[n * 2 + 1];
    pot[n * 2] = s0; pot[n * 2 + 1] = s1;
  }
  __syncthreads();
  for (int e = 0; e < NE; ++e) {
    for (int s = cnt[e] + t; s < padc[e]; s += 256) {
      ptok[soff[e] + s] = 0; pw[soff[e] + s] = 0.f;   // padding: token 0, weight 0
    }
  }
}

// LDS layout both GEMMs: rows x 8 chunks of 16B (64 bf16). Physical chunk of
// row r holds logical chunk p ^ (r&7): async writes stay lane-contiguous,
// fragment ds_read_b128 sees only 2-way bank aliasing (free, m136).
// XCD-grouped mapping: all y-blocks of one A-tile (i4) land on one XCD
// (assumes round-robin bid%8 -> XCD; perf-only heuristic, m157/m192) so the
// A-tile stays in that XCD's 4MB L2 across its 16 (resp 8) consumers.

// ---------------- GEMM1: 128 slots x 64 f (gate+up interleaved per-16).
// acc[4][4], 32 MFMA/wave/K-step. 640 blocks.
__global__ __launch_bounds__(256, 2) void k_gemm1(
    const unsigned short* __restrict__ xb, const unsigned short* __restrict__ gupb,
    unsigned short* __restrict__ hmid, const int* __restrict__ ptok,
    const int* __restrict__ ctrl) {
  int b = blockIdx.x;
  int xcd = b & 7;
  int j = b >> 3;                 // 0..79
  int i4 = xcd + 8 * (j >> 4);    // A-tile index, all its y's on XCD (i4%8)
  int y = j & 15;
  if (i4 >= ctrl[1]) return;
  int wlv = ctrl[40 + i4];
  int e = wlv >> 16;
  int mt = wlv & 0xffff;
  int base = ctrl[24 + e] + mt * MT;
  int f0 = y * 64;

  __shared__ unsigned short As[MT * BK];    // 16 KB
  __shared__ unsigned short Bs[128 * BK];   // 16 KB
  __shared__ int toks[MT];

  int t = threadIdx.x;
  if (t < MT) toks[t] = ptok[base + t];
  __syncthreads();

  int lane = t & 63;
  int wave = t >> 6;
  int wm = wave >> 1, wn = wave & 1;
  int lm = lane & 15, lh = lane >> 4;

  f32x4 acc[4][4] = {};
  const unsigned short* gbase = gupb + (size_t)e * 2 * FDIM * HID;

  for (int k0 = 0; k0 < HID; k0 += BK) {
    // A: 128 rows x 64 bf16, async token gather
#pragma unroll
    for (int i = 0; i < 4; ++i) {
      int q = i * 256 + t;
      int r = q >> 3;
      int cl = (q & 7) ^ (r & 7);
      gl2lds16(xb + (size_t)toks[r] * HID + k0 + cl * 8, &As[(q & ~63) * 8]);
    }
    // B: 128 rows; row r -> type=(r>>4)&1 (gate/up), fb=r>>5, fl=r&15
#pragma unroll
    for (int i = 0; i < 4; ++i) {
      int q = i * 256 + t;
      int r = q >> 3;
      int cl = (q & 7) ^ (r & 7);
      int grow = ((r >> 4) & 1) * FDIM + f0 + ((r >> 5) << 4) + (r & 15);
      gl2lds16(gbase + (size_t)grow * HID + k0 + cl * 8, &Bs[(q & ~63) * 8]);
    }
    __syncthreads();
#pragma unroll
    for (int kk = 0; kk < 2; ++kk) {
      bf16x8 af[4], bfr[4];
#pragma unroll
      for (int rb = 0; rb < 4; ++rb) {
        int row = wm * 64 + rb * 16 + lm;
        int p = (kk * 4 + lh) ^ (row & 7);
        af[rb] = *(const bf16x8*)(&As[row * BK + p * 8]);
      }
#pragma unroll
      for (int cc = 0; cc < 4; ++cc) {
        int row = wn * 64 + cc * 16 + lm;
        int p = (kk * 4 + lh) ^ (row & 7);
        bfr[cc] = *(const bf16x8*)(&Bs[row * BK + p * 8]);
      }
#pragma unroll
      for (int rb = 0; rb < 4; ++rb) {
#pragma unroll
        for (int cc = 0; cc < 4; ++cc)
          acc[rb][cc] = __builtin_amdgcn_mfma_f32_16x16x32_bf16(af[rb], bfr[cc], acc[rb][cc], 0, 0, 0);
      }
    }
    __syncthreads();
  }
  // epilogue: cc = {gate fb0, up fb0, gate fb1, up fb1}; f = f0+wn*32+fb*16+lm
#pragma unroll
  for (int rb = 0; rb < 4; ++rb) {
    int slot = base + wm * 64 + rb * 16 + lh * 4;
#pragma unroll
    for (int fb = 0; fb < 2; ++fb) {
      f32x4 g = acc[rb][fb * 2];
      f32x4 u = acc[rb][fb * 2 + 1];
      int f = f0 + wn * 32 + fb * 16 + lm;
#pragma unroll
      for (int reg = 0; reg < 4; ++reg) {
        float gv = g[reg];
        float hm = gv / (1.f + __expf(-gv)) * u[reg];
        hmid[(size_t)(slot + reg) * FDIM + f] = f2bf(hm);
      }
    }
  }
}

// ---------------- GEMM2: 128 slots x 128 h -> yb bf16. 320 blocks.
__global__ __launch_bounds__(256, 2) void k_gemm2(
    const unsigned short* __restrict__ hmid, const unsigned short* __restrict__ dwnb,
    unsigned short* __restrict__ yb, const int* __restrict__ ctrl) {
  int b = blockIdx.x;
  int xcd = b & 7;
  int j = b >> 3;                 // 0..39
  int i4 = xcd + 8 * (j >> 3);
  int y = j & 7;
  if (i4 >= ctrl[1]) return;
  int wlv = ctrl[40 + i4];
  int e = wlv >> 16;
  int mt = wlv & 0xffff;
  int base = ctrl[24 + e] + mt * MT;
  int h0 = y * 128;

  __shared__ unsigned short As[MT * BK];    // 16 KB
  __shared__ unsigned short Bs[128 * BK];   // 16 KB

  int t = threadIdx.x;
  int lane = t & 63;
  int wave = t >> 6;
  int wm = wave >> 1, wn = wave & 1;
  int lm = lane & 15, lh = lane >> 4;

  f32x4 acc[4][4] = {};
  const unsigned short* dbase = dwnb + (size_t)e * HID * FDIM;

  for (int k0 = 0; k0 < FDIM; k0 += BK) {
#pragma unroll
    for (int i = 0; i < 4; ++i) {
      int q = i * 256 + t;
      int r = q >> 3;
      int cl = (q & 7) ^ (r & 7);
      gl2lds16(hmid + (size_t)(base + r) * FDIM + k0 + cl * 8, &As[(q & ~63) * 8]);
    }
#pragma unroll
    for (int i = 0; i < 4; ++i) {
      int q = i * 256 + t;
      int r = q >> 3;
      int cl = (q & 7) ^ (r & 7);
      gl2lds16(dbase + (size_t)(h0 + r) * FDIM + k0 + cl * 8, &Bs[(q & ~63) * 8]);
    }
    __syncthreads();
#pragma unroll
    for (int kk = 0; kk < 2; ++kk) {
      bf16x8 af[4], bfr[4];
#pragma unroll
      for (int rb = 0; rb < 4; ++rb) {
        int row = wm * 64 + rb * 16 + lm;
        int p = (kk * 4 + lh) ^ (row & 7);
        af[rb] = *(const bf16x8*)(&As[row * BK + p * 8]);
      }
#pragma unroll
      for (int cc = 0; cc < 4; ++cc) {
        int row = wn * 64 + cc * 16 + lm;
        int p = (kk * 4 + lh) ^ (row & 7);
        bfr[cc] = *(const bf16x8*)(&Bs[row * BK + p * 8]);
      }
#pragma unroll
      for (int rb = 0; rb < 4; ++rb) {
#pragma unroll
        for (int cc = 0; cc < 4; ++cc)
          acc[rb][cc] = __builtin_amdgcn_mfma_f32_16x16x32_bf16(af[rb], bfr[cc], acc[rb][cc], 0, 0, 0);
      }
    }
    __syncthreads();
  }
#pragma unroll
  for (int rb = 0; rb < 4; ++rb) {
    int slot = base + wm * 64 + rb * 16 + lh * 4;
#pragma unroll
    for (int cc = 0; cc < 4; ++cc) {
      int h = h0 + wn * 64 + cc * 16 + lm;
#pragma unroll
      for (int reg = 0; reg < 4; ++reg)
        yb[(size_t)(slot + reg) * HID + h] = f2bf(acc[rb][cc][reg]);
    }
  }
}

// ---------------- Combine: out[n] = w0*y[p0] + w1*y[p1]
__global__ __launch_bounds__(256) void k_combine(
    const unsigned short* __restrict__ yb, const float* __restrict__ pw,
    const int* __restrict__ pot, float* __restrict__ out) {
  int n = blockIdx.x;
  int t = threadIdx.x;
  int p0 = pot[n * 2], p1 = pot[n * 2 + 1];
  float w0 = pw[p0], w1 = pw[p1];
  int h = t * 4;
  ushort4 a = *(const ushort4*)(yb + (size_t)p0 * HID + h);
  ushort4 b = *(const ushort4*)(yb + (size_t)p1 * HID + h);
  float4 o;
  o.x = w0 * bf2f(a.x) + w1 * bf2f(b.x);
  o.y = w0 * bf2f(a.y) + w1 * bf2f(b.y);
  o.z = w0 * bf2f(a.z) + w1 * bf2f(b.z);
  o.w = w0 * bf2f(a.w) + w1 * bf2f(b.w);
  *(float4*)(out + (size_t)n * HID + h) = o;
}

extern "C" void kernel_launch(void* const* d_in, const int* in_sizes, int n_in,
                              void* d_out, int out_size, void* d_ws, size_t ws_size,
                              hipStream_t stream) {
  (void)in_sizes; (void)n_in; (void)out_size; (void)ws_size;
  const float* x   = (const float*)d_in[0];
  const float* gw  = (const float*)d_in[1];
  const float* gup = (const float*)d_in[2];
  const float* dwn = (const float*)d_in[3];
  const float* sim = (const float*)d_in[4];
  float* out = (float*)d_out;

  char* w = (char*)d_ws;
  int* ctrl = (int*)w;
  size_t off = 512;
  unsigned short* xb = (unsigned short*)(w + off); off += (size_t)N_TOK * HID * 2;
  float* topw = (float*)(w + off); off += (size_t)N_TOK * 2 * 4;
  int*   topi = (int*)(w + off);   off += (size_t)N_TOK * 2 * 4;
  int*   ptok = (int*)(w + off);   off += (size_t)PAIR_CAP * 4;
  float* pw   = (float*)(w + off); off += (size_t)PAIR_CAP * 4;
  int*   pot  = (int*)(w + off);   off += (size_t)N_TOK * 2 * 4;
  unsigned short* hmid = (unsigned short*)(w + off); off += (size_t)PAIR_CAP * FDIM * 2;
  unsigned short* yb   = (unsigned short*)(w + off); off += (size_t)PAIR_CAP * HID * 2;
  unsigned short* gupb = (unsigned short*)(w + off); off += (size_t)NE * 2 * FDIM * HID * 2;
  unsigned short* dwnb = (unsigned short*)(w + off); off += (size_t)NE * HID * FDIM * 2;

  int n4g = NE * 2 * FDIM * HID / 4;   // 4,194,304 float4s
  int n4d = NE * HID * FDIM / 4;       // 2,097,152 float4s
  int cvtBlocks = (n4g + n4d) / 256;   // 24576
  k_rc<<<512 + cvtBlocks, 256, 0, stream>>>(x, gw, xb, topw, topi,
                                            gup, gupb, n4g, dwn, dwnb, n4d);
  k_pairs<<<1, 256, 0, stream>>>(sim, topi, topw, ctrl, ptok, pw, pot);
  k_gemm1<<<dim3(640), 256, 0, stream>>>(xb, gupb, hmid, ptok, ctrl);
  k_gemm2<<<dim3(320), 256, 0, stream>>>(hmid, dwnb, yb, ctrl);
  k_combine<<<N_TOK, 256, 0, stream>>>(yb, pw, pot, out);
}